// Round 12
// baseline (324.639 us; speedup 1.0000x reference)
//
#include <hip/hip_runtime.h>

#define B_ 4
#define H_ 16
#define SQ 1024
#define SK 1024
#define DHD 64
#define E_ 1024

typedef _Float16 half_t;
typedef __attribute__((ext_vector_type(8))) _Float16 half8;
typedef __attribute__((ext_vector_type(4))) _Float16 half4;
typedef __attribute__((ext_vector_type(4))) float f32x4;

static __device__ __forceinline__ f32x4 mfma16h(half8 a, half8 b, f32x4 c) {
  return __builtin_amdgcn_mfma_f32_16x16x32_f16(a, b, c, 0, 0, 0);
}

// ---- fused prep: emb/Wq fp32->fp16, K -> -K fp16, V -> V^T fp16 ----
#define QW_BLOCKS 2560  // 2048 (emb) + 512 (wq)
__global__ __launch_bounds__(256) void prep_kernel(const float* __restrict__ emb,
                                                   const float* __restrict__ wq,
                                                   const float* __restrict__ K,
                                                   const float* __restrict__ V,
                                                   half_t* __restrict__ emb_h,
                                                   half_t* __restrict__ wq_h,
                                                   half_t* __restrict__ khn,
                                                   half_t* __restrict__ vt) {
  int bid = blockIdx.x, tid = threadIdx.x;
  if (bid < QW_BLOCKS) {
    int i = bid * 256 + tid;
    const float* src;
    half_t* dst;
    if (i < (B_ * SQ * E_ / 8)) {
      src = emb;
      dst = emb_h;
    } else {
      i -= B_ * SQ * E_ / 8;
      src = wq;
      dst = wq_h;
    }
    size_t off = (size_t)i * 8;
    f32x4 v0 = *(const f32x4*)(src + off);
    f32x4 v1 = *(const f32x4*)(src + off + 4);
    half8 h;
#pragma unroll
    for (int j = 0; j < 4; ++j) {
      h[j] = (half_t)v0[j];
      h[4 + j] = (half_t)v1[j];
    }
    *(half8*)(dst + off) = h;
    return;
  }
  bid -= QW_BLOCKS;  // 1024 kv blocks
  int bh = bid >> 4, kt = bid & 15;
  const float* ks = K + ((size_t)bh * SK + kt * 64) * DHD;
  half_t* kd = khn + ((size_t)bh * SK + kt * 64) * DHD;
#pragma unroll
  for (int j = 0; j < 2; ++j) {
    int base = j * 2048 + tid * 8;
    f32x4 a = *(const f32x4*)(ks + base);
    f32x4 b = *(const f32x4*)(ks + base + 4);
    half8 h;
#pragma unroll
    for (int r = 0; r < 4; ++r) {
      h[r] = (half_t)(-a[r]);
      h[4 + r] = (half_t)(-b[r]);
    }
    *(half8*)(kd + base) = h;
  }
  __shared__ float tile[64][65];
  const float* vs = V + ((size_t)bh * SK + kt * 64) * DHD;
#pragma unroll
  for (int i = 0; i < 16; ++i) {
    int idx = i * 256 + tid;
    tile[idx >> 6][idx & 63] = vs[idx];
  }
  __syncthreads();
#pragma unroll
  for (int i = 0; i < 16; ++i) {
    int idx = i * 256 + tid;
    int d = idx >> 6, kk = idx & 63;
    vt[((size_t)bh * DHD + d) * SK + kt * 64 + kk] = (half_t)tile[kk][d];
  }
}

// ---- q projection: q = (emb @ Wq^T + bq) * 0.125 ----
__global__ __launch_bounds__(256) void proj_kernel(const half_t* __restrict__ emb,
                                                   const half_t* __restrict__ wq,
                                                   const float* __restrict__ bq,
                                                   half_t* __restrict__ qh) {
  int bid = blockIdx.x;  // 1024, XCD-swizzled
  int xcd = bid & 7, jj = bid >> 3;
  int mt = xcd * 8 + (jj >> 4);
  int nt = jj & 15;
  int tid = threadIdx.x, wid = tid >> 6, lane = tid & 63;
  int lr = lane & 15, lg = lane >> 4;
  int m0 = mt * 64 + (wid >> 1) * 32;
  int n0 = nt * 64 + (wid & 1) * 32;
  f32x4 acc[2][2];
#pragma unroll
  for (int i = 0; i < 2; ++i)
#pragma unroll
    for (int j = 0; j < 2; ++j) acc[i][j] = (f32x4){0.f, 0.f, 0.f, 0.f};

  for (int kk = 0; kk < E_; kk += 32) {
    half8 a[2], b[2];
#pragma unroll
    for (int g = 0; g < 2; ++g) {
      a[g] = *(const half8*)(emb + (size_t)(m0 + g * 16 + lr) * E_ + kk + lg * 8);
      b[g] = *(const half8*)(wq + (size_t)(n0 + g * 16 + lr) * E_ + kk + lg * 8);
    }
#pragma unroll
    for (int i = 0; i < 2; ++i)
#pragma unroll
      for (int j = 0; j < 2; ++j) acc[i][j] = mfma16h(a[i], b[j], acc[i][j]);
  }
#pragma unroll
  for (int i = 0; i < 2; ++i)
#pragma unroll
    for (int j = 0; j < 2; ++j)
#pragma unroll
      for (int r = 0; r < 4; ++r) {
        int m = m0 + i * 16 + lg * 4 + r;  // row=(lane>>4)*4+r
        int n = n0 + j * 16 + lr;          // col=lane&15
        float v = (acc[i][j][r] + bq[n]) * 0.125f;
        int b = m >> 10, sq = m & 1023, h = n >> 6, dd = n & 63;
        qh[((size_t)(b * H_ + h) * SQ + sq) * DHD + dd] = (half_t)v;
      }
}

// ---- kernel 1: p = exp(S - M), wave-autonomous, zero barriers / zero LDS ----
// One wave = 16 q-rows x 256 k. T = M - K.q via MFMA with M as C-input
// (khn = -K). All 16 M-loads (f32x4, 16B/lane) issue up-front into regs.
// p stored to blob in MFMA lane order -> 512B fully-coalesced stores.
// blob[bh][qt][kc][kt][lane][4] fp16 = 128 MB total (full P panel).
__global__ __launch_bounds__(256, 3) void pexp_kernel(const half_t* __restrict__ qh,
                                                      const half_t* __restrict__ khn,
                                                      const float* __restrict__ M,
                                                      half_t* __restrict__ blob,
                                                      float* __restrict__ rs_part) {
  int bid = blockIdx.x;  // 4096 = 8 XCD x 512
  int x = bid & 7, j = bid >> 3;
  int bh = x * 8 + (j >> 6);  // 8 bh per XCD (q/K L2-resident)
  int tid = threadIdx.x, wid = tid >> 6, lane = tid & 63;
  int lr = lane & 15, lg = lane >> 4;
  int u = (j & 63) * 4 + wid;  // 256 units per bh: 64 qt x 4 kc
  int qt = u >> 2, kc = u & 3;
  int q0 = qt * 16;

  // q B-fragments (one q-row per lr)
  const half_t* qrow = qh + ((size_t)bh * SQ + q0 + lr) * DHD;
  half8 qf0 = *(const half8*)(qrow + lg * 8);
  half8 qf1 = *(const half8*)(qrow + 32 + lg * 8);

  // burst-issue all 16 M fragment loads (C-layout: lane -> M[q0+lr][k0+lg*4..+3])
  const float* mrow = M + ((size_t)bh * SQ + q0 + lr) * SK + kc * 256 + lg * 4;
  f32x4 ms[16];
#pragma unroll
  for (int kt = 0; kt < 16; ++kt) ms[kt] = *(const f32x4*)(mrow + kt * 16);

  const half_t* kbase = khn + ((size_t)bh * SK + kc * 256 + lr) * DHD + lg * 8;
  half_t* bout = blob + ((size_t)((bh * 64 + qt) * 4 + kc) * 16) * 256 + lane * 4;
  float rsum = 0.f;
#pragma unroll
  for (int kt = 0; kt < 16; ++kt) {
    const half_t* kr = kbase + (size_t)kt * 16 * DHD;
    half8 k0 = *(const half8*)(kr);
    half8 k1 = *(const half8*)(kr + 32);
    f32x4 T = ms[kt];  // T = M - K.q
    T = mfma16h(k0, qf0, T);
    T = mfma16h(k1, qf1, T);
    half4 ph;
#pragma unroll
    for (int r = 0; r < 4; ++r) {
      float p = __expf(-T[r]);  // p = exp(S - M), bounded (validated r6+)
      rsum += p;
      ph[r] = (half_t)p;
    }
    *(half4*)(bout + (size_t)kt * 256) = ph;
  }
  // row q = lr: sum over lg groups
  rsum += __shfl_xor(rsum, 16);
  rsum += __shfl_xor(rsum, 32);
  if (lg == 0) rs_part[((bh * 64 + qt) * 4 + kc) * 16 + lr] = rsum;
}

// ---- kernel 2: rowscale + PV + colmax partials + ctx store ----
__global__ __launch_bounds__(256, 4) void pv_kernel(const half_t* __restrict__ blob,
                                                    const float* __restrict__ rs_part,
                                                    const half_t* __restrict__ vt,
                                                    const float* __restrict__ dpm,
                                                    float* __restrict__ out,
                                                    float* __restrict__ pm) {
  __shared__ float red[64];
  __shared__ float rowscale[16];
  int bid = blockIdx.x;  // 4096 = 8 XCD x 512
  int x = bid & 7, j = bid >> 3;
  int bh = x * 8 + (j >> 6);
  int qt = j & 63;
  int q0 = qt * 16;
  int b = bh >> 4, h = bh & 15;
  int tid = threadIdx.x, wid = tid >> 6, lane = tid & 63;
  int lr = lane & 15, lg = lane >> 4;

  if (tid < 64) red[tid] = rs_part[(bh * 64 + qt) * 64 + tid];
  __syncthreads();
  if (tid < 16)
    rowscale[tid] =
        dpm[b * SQ + q0 + tid] / (red[tid] + red[16 + tid] + red[32 + tid] + red[48 + tid]);
  __syncthreads();

  const half_t* qtblob = blob + (size_t)(bh * 64 + qt) * 64 * 256;
  float rs = rowscale[lr];

  // PV: 4 waves = 4 d-tiles of 16. B-frag assembled from blob lane-order:
  // lane (lr,lg) needs k = t*32 + lg*8 + j  ->  kt_g = 2t + (lg>>1),
  // slots (lg&1)*2*16+lr and +16 within that kt block (4 halves each).
  int d0 = wid * 16;
  const half_t* vrow = vt + ((size_t)bh * DHD + d0 + lr) * SK;
  int bsel = ((lg & 1) * 32 + lr) * 4;
  f32x4 acc = (f32x4){0.f, 0.f, 0.f, 0.f};
#pragma unroll 8
  for (int t = 0; t < 32; ++t) {
    int ktg = t * 2 + (lg >> 1);
    const half_t* bp_ = qtblob + ktg * 256 + bsel;
    half4 p0 = *(const half4*)(bp_);
    half4 p1 = *(const half4*)(bp_ + 64);
    half8 bp;
#pragma unroll
    for (int r = 0; r < 4; ++r) {
      bp[r] = p0[r];
      bp[4 + r] = p1[r];
    }
    half8 av = *(const half8*)(vrow + t * 32 + lg * 8);
    acc = mfma16h(av, bp, acc);
  }
  f32x4 res;
#pragma unroll
  for (int r = 0; r < 4; ++r) res[r] = acc[r] * rs;
  *(f32x4*)(out + ((size_t)b * SQ + q0 + lr) * E_ + h * DHD + d0 + lg * 4) = res;

  // colmax partial over the 16 q-rows; wave wid handles kc = wid (256 k)
  const half_t* cb = qtblob + wid * 16 * 256 + lane * 4;
  float* pmb = pm + ((size_t)bh * 64 + qt) * SK + wid * 256;
#pragma unroll
  for (int ktl = 0; ktl < 16; ++ktl) {
    half4 pv = *(const half4*)(cb + ktl * 256);
    f32x4 f;
#pragma unroll
    for (int r = 0; r < 4; ++r) f[r] = (float)pv[r] * rs;
#pragma unroll
    for (int step = 1; step < 16; step <<= 1)
#pragma unroll
      for (int r = 0; r < 4; ++r) f[r] = fmaxf(f[r], __shfl_xor(f[r], step));
    if (lr == 0) *(f32x4*)(pmb + ktl * 16 + lg * 4) = f;
  }
}

// ---- target_score: out[b][k] = sum_h max_qt pm[bh][qt][k] ----
__global__ __launch_bounds__(256) void tscore_kernel(const float* __restrict__ pm,
                                                     float* __restrict__ out) {
  int bb = blockIdx.x;  // 64 = 4 b x 16 k-chunks
  int b = bb >> 4, kq = bb & 15;
  int t = threadIdx.x;
  int kl = t & 63, hg = t >> 6;  // 4 h-groups x 64 k
  int k = kq * 64 + kl;
  float s = 0.f;
#pragma unroll
  for (int hh = hg * 4; hh < hg * 4 + 4; ++hh) {
    const float* p = pm + ((size_t)(b * H_ + hh) * 64) * SK + k;
    float mx = 0.f;
#pragma unroll
    for (int qt = 0; qt < 64; ++qt) mx = fmaxf(mx, p[(size_t)qt * SK]);
    s += mx;
  }
  __shared__ float red[4][64];
  red[hg][kl] = s;
  __syncthreads();
  if (t < 64)
    out[(size_t)B_ * SQ * E_ + b * SK + kq * 64 + t] =
        red[0][t] + red[1][t] + red[2][t] + red[3][t];
}

extern "C" void kernel_launch(void* const* d_in, const int* in_sizes, int n_in,
                              void* d_out, int out_size, void* d_ws, size_t ws_size,
                              hipStream_t stream) {
  const float* dp_emb = (const float*)d_in[0];
  const float* dp_mask = (const float*)d_in[1];
  const float* K = (const float*)d_in[2];
  const float* V = (const float*)d_in[3];
  const float* M = (const float*)d_in[4];
  const float* Wq = (const float*)d_in[5];
  const float* bq = (const float*)d_in[6];
  float* out = (float*)d_out;

  char* ws = (char*)d_ws;
  half_t* q_h = (half_t*)(ws);                     // 8 MB   [BH,Sq,64]
  half_t* k_hn = (half_t*)(ws + (8ull << 20));     // 8 MB   [BH,Sk,64] (negated)
  half_t* vt_h = (half_t*)(ws + (16ull << 20));    // 8 MB   [BH,64,Sk]
  half_t* emb_h = (half_t*)(ws + (24ull << 20));   // 8 MB   [B*Sq,E]
  half_t* wq_h = (half_t*)(ws + (32ull << 20));    // 2 MB   [E,E]
  half_t* blob = (half_t*)(ws + (34ull << 20));    // 128 MB [BH,64qt,4kc,16kt,256] p fp16
  float* rs_part = (float*)(ws + (164ull << 20));  // 1 MB   [BH,64qt,4kc,16]
  float* pm = (float*)(ws + (166ull << 20));       // 16 MB  [BH,64qt,Sk] colmax partials

  prep_kernel<<<QW_BLOCKS + B_ * H_ * 16, 256, 0, stream>>>(dp_emb, Wq, K, V, emb_h, wq_h,
                                                            k_hn, vt_h);
  proj_kernel<<<1024, 256, 0, stream>>>(emb_h, wq_h, bq, q_h);
  pexp_kernel<<<4096, 256, 0, stream>>>(q_h, k_hn, M, blob, rs_part);
  pv_kernel<<<4096, 256, 0, stream>>>(blob, rs_part, vt_h, dp_mask, out, pm);
  tscore_kernel<<<64, 256, 0, stream>>>(pm, out);
}

// Round 13
// 213.181 us; speedup vs baseline: 1.5228x; 1.5228x over previous
//
#include <hip/hip_runtime.h>

#define B_ 4
#define H_ 16
#define SQ 1024
#define SK 1024
#define DHD 64
#define E_ 1024

typedef _Float16 half_t;
typedef __attribute__((ext_vector_type(8))) _Float16 half8;
typedef __attribute__((ext_vector_type(4))) _Float16 half4;
typedef __attribute__((ext_vector_type(4))) float f32x4;

static __device__ __forceinline__ f32x4 mfma16h(half8 a, half8 b, f32x4 c) {
  return __builtin_amdgcn_mfma_f32_16x16x32_f16(a, b, c, 0, 0, 0);
}
// LDS-only barrier: do NOT drain vmcnt (keeps the upfront M loads in flight;
// __syncthreads would emit s_waitcnt vmcnt(0) and kill the prefetch)
static __device__ __forceinline__ void lds_barrier() {
  asm volatile("s_waitcnt lgkmcnt(0)" ::: "memory");
  __builtin_amdgcn_s_barrier();
}

// ---- fused prep: emb/Wq fp32->fp16, K -> -K fp16, V -> V^T fp16 ----
#define QW_BLOCKS 2560  // 2048 (emb) + 512 (wq)
__global__ __launch_bounds__(256) void prep_kernel(const float* __restrict__ emb,
                                                   const float* __restrict__ wq,
                                                   const float* __restrict__ K,
                                                   const float* __restrict__ V,
                                                   half_t* __restrict__ emb_h,
                                                   half_t* __restrict__ wq_h,
                                                   half_t* __restrict__ khn,
                                                   half_t* __restrict__ vt) {
  int bid = blockIdx.x, tid = threadIdx.x;
  if (bid < QW_BLOCKS) {
    int i = bid * 256 + tid;
    const float* src;
    half_t* dst;
    if (i < (B_ * SQ * E_ / 8)) {
      src = emb;
      dst = emb_h;
    } else {
      i -= B_ * SQ * E_ / 8;
      src = wq;
      dst = wq_h;
    }
    size_t off = (size_t)i * 8;
    f32x4 v0 = *(const f32x4*)(src + off);
    f32x4 v1 = *(const f32x4*)(src + off + 4);
    half8 h;
#pragma unroll
    for (int j = 0; j < 4; ++j) {
      h[j] = (half_t)v0[j];
      h[4 + j] = (half_t)v1[j];
    }
    *(half8*)(dst + off) = h;
    return;
  }
  bid -= QW_BLOCKS;  // 1024 kv blocks
  int bh = bid >> 4, kt = bid & 15;
  const float* ks = K + ((size_t)bh * SK + kt * 64) * DHD;
  half_t* kd = khn + ((size_t)bh * SK + kt * 64) * DHD;
#pragma unroll
  for (int j = 0; j < 2; ++j) {
    int base = j * 2048 + tid * 8;
    f32x4 a = *(const f32x4*)(ks + base);
    f32x4 b = *(const f32x4*)(ks + base + 4);
    half8 h;
#pragma unroll
    for (int r = 0; r < 4; ++r) {
      h[r] = (half_t)(-a[r]);
      h[4 + r] = (half_t)(-b[r]);
    }
    *(half8*)(kd + base) = h;
  }
  __shared__ float tile[64][65];
  const float* vs = V + ((size_t)bh * SK + kt * 64) * DHD;
#pragma unroll
  for (int i = 0; i < 16; ++i) {
    int idx = i * 256 + tid;
    tile[idx >> 6][idx & 63] = vs[idx];
  }
  __syncthreads();
#pragma unroll
  for (int i = 0; i < 16; ++i) {
    int idx = i * 256 + tid;
    int d = idx >> 6, kk = idx & 63;
    vt[((size_t)bh * DHD + d) * SK + kt * 64 + kk] = (half_t)tile[kk][d];
  }
}

// ---- q projection: q = (emb @ Wq^T + bq) * 0.125 * log2(e)  (exp2-folded) ----
__global__ __launch_bounds__(256) void proj_kernel(const half_t* __restrict__ emb,
                                                   const half_t* __restrict__ wq,
                                                   const float* __restrict__ bq,
                                                   half_t* __restrict__ qh) {
  int bid = blockIdx.x;  // 1024, XCD-swizzled
  int xcd = bid & 7, jj = bid >> 3;
  int mt = xcd * 8 + (jj >> 4);
  int nt = jj & 15;
  int tid = threadIdx.x, wid = tid >> 6, lane = tid & 63;
  int lr = lane & 15, lg = lane >> 4;
  int m0 = mt * 64 + (wid >> 1) * 32;
  int n0 = nt * 64 + (wid & 1) * 32;
  f32x4 acc[2][2];
#pragma unroll
  for (int i = 0; i < 2; ++i)
#pragma unroll
    for (int j = 0; j < 2; ++j) acc[i][j] = (f32x4){0.f, 0.f, 0.f, 0.f};

  for (int kk = 0; kk < E_; kk += 32) {
    half8 a[2], b[2];
#pragma unroll
    for (int g = 0; g < 2; ++g) {
      a[g] = *(const half8*)(emb + (size_t)(m0 + g * 16 + lr) * E_ + kk + lg * 8);
      b[g] = *(const half8*)(wq + (size_t)(n0 + g * 16 + lr) * E_ + kk + lg * 8);
    }
#pragma unroll
    for (int i = 0; i < 2; ++i)
#pragma unroll
      for (int j = 0; j < 2; ++j) acc[i][j] = mfma16h(a[i], b[j], acc[i][j]);
  }
#pragma unroll
  for (int i = 0; i < 2; ++i)
#pragma unroll
    for (int j = 0; j < 2; ++j)
#pragma unroll
      for (int r = 0; r < 4; ++r) {
        int m = m0 + i * 16 + lg * 4 + r;  // row=(lane>>4)*4+r
        int n = n0 + j * 16 + lr;          // col=lane&15
        float v = (acc[i][j][r] + bq[n]) * 0.180336880f;  // 0.125 * log2(e)
        int b = m >> 10, sq = m & 1023, h = n >> 6, dd = n & 63;
        qh[((size_t)(b * H_ + h) * SQ + sq) * DHD + dd] = (half_t)v;
      }
}

// ---- fused attention: upfront M-prefetch, exp-factored softmax, no atomics ----
// p = exp(S-M) = exp2(-T)*exp(-M), T = K~.q' (khn=-K, q'=q*0.125*log2e).
// ALL 16 M f32x4 loads per thread issue at kernel entry (64 VGPRs in flight,
// ~256KB/CU outstanding) and are consumed after the whole QK^T/exp phase --
// ~2000+ cycles of MFMA/exp2 cover the ~900cy HBM latency completely.
__global__ __launch_bounds__(512, 4) void attn_kernel(const half_t* __restrict__ qh,
                                                      const half_t* __restrict__ khn,
                                                      const half_t* __restrict__ vt,
                                                      const float* __restrict__ M,
                                                      const float* __restrict__ dpm,
                                                      float* __restrict__ out,
                                                      float* __restrict__ pm) {
  __shared__ half_t panel[32][1032];  // eS then p, fp16 (+8 pad)
  __shared__ float rowscale[32];

  int bid = blockIdx.x;
  int x = bid & 7, j = bid >> 3;  // 2048 blocks = 8 XCD x 256
  int bh = x * 8 + (j >> 5);      // 8 bh per XCD (K/V/q L2-resident)
  int qt = j & 31;
  int q0 = qt << 5;
  int b = bh >> 4, h = bh & 15;

  int tid = threadIdx.x, wid = tid >> 6, lane = tid & 63;
  int lr = lane & 15, lg = lane >> 4;

  // ---- upfront M prefetch: B-map row qr = wid*4+lg, 16 lanes (lr) per row ----
  int qr = wid * 4 + lg;
  const float* mrow = M + ((size_t)bh * SQ + q0 + qr) * SK + lr * 4;
  f32x4 ms[16];
#pragma unroll
  for (int i = 0; i < 16; ++i) ms[i] = *(const f32x4*)(mrow + i * 64);
  __builtin_amdgcn_sched_barrier(0);  // pin: loads must not sink below here

  // q fragments (A-mapping)
  const half_t* qbase = qh + ((size_t)bh * SQ + q0) * DHD;
  half8 aq[2][2];
#pragma unroll
  for (int qg = 0; qg < 2; ++qg)
#pragma unroll
    for (int dh = 0; dh < 2; ++dh)
      aq[qg][dh] = *(const half8*)(qbase + (size_t)(qg * 16 + lr) * DHD + dh * 32 + lg * 8);

  // ---- phase A: eS = exp2(-T) panel. wave owns k in [wid*128, +128) ----
  int kc0 = wid * 128;
#pragma unroll
  for (int kt = 0; kt < 8; ++kt) {
    const half_t* kr = khn + ((size_t)bh * SK + kc0 + kt * 16 + lr) * DHD + lg * 8;
    half8 k0 = *(const half8*)(kr);
    half8 k1 = *(const half8*)(kr + 32);
#pragma unroll
    for (int qg = 0; qg < 2; ++qg) {
      f32x4 T = (f32x4){0.f, 0.f, 0.f, 0.f};
      T = mfma16h(k0, aq[qg][0], T);
      T = mfma16h(k1, aq[qg][1], T);
      half4 ph;
#pragma unroll
      for (int r = 0; r < 4; ++r) ph[r] = (half_t)exp2f(-T[r]);  // eS = exp(S)
      *(half4*)&panel[qg * 16 + lr][kc0 + kt * 16 + lg * 4] = ph;
    }
  }
  lds_barrier();  // panel visible; M loads still in flight until first ms use

  // ---- phase B: p = eS * exp(-M) from prefetched regs; in-register row sums ----
  half_t* prow = &panel[qr][lr * 4];
  float rsum = 0.f;
#pragma unroll
  for (int i = 0; i < 16; ++i) {
    f32x4 m = ms[i];
    half4 es = *(const half4*)(prow + i * 64);
    half4 ph;
#pragma unroll
    for (int r = 0; r < 4; ++r) {
      float p = (float)es[r] * __expf(-m[r]);
      rsum += p;
      ph[r] = (half_t)p;
    }
    *(half4*)(prow + i * 64) = ph;
  }
  rsum += __shfl_xor(rsum, 1);
  rsum += __shfl_xor(rsum, 2);
  rsum += __shfl_xor(rsum, 4);
  rsum += __shfl_xor(rsum, 8);
  if (lr == 0) rowscale[qr] = dpm[b * SQ + q0 + qr] / rsum;
  lds_barrier();

  // ---- phase C: PV (8 waves = 2 qg x 4 d-tiles) ----
  int qg = wid >> 2, d0 = (wid & 3) * 16;
  const half_t* vrow = vt + ((size_t)bh * DHD + d0 + lr) * SK;
  f32x4 acc = (f32x4){0.f, 0.f, 0.f, 0.f};
#pragma unroll 8
  for (int ks = 0; ks < SK; ks += 32) {
    half8 av = *(const half8*)(vrow + ks + lg * 8);
    half8 bp = *(const half8*)&panel[qg * 16 + lr][ks + lg * 8];
    acc = mfma16h(av, bp, acc);
  }
  float rs = rowscale[qg * 16 + lr];
  f32x4 res;
#pragma unroll
  for (int r = 0; r < 4; ++r) res[r] = acc[r] * rs;
  *(f32x4*)(out + ((size_t)b * SQ + q0 + qg * 16 + lr) * E_ + h * DHD + d0 + lg * 4) = res;

  // ---- colmax partial over this block's 32 q-rows -> plain coalesced store ----
  {
    int c = tid * 2;
    float m0 = 0.f, m1 = 0.f;
#pragma unroll 8
    for (int r = 0; r < 32; ++r) {
      float w = rowscale[r];
      m0 = fmaxf(m0, (float)panel[r][c] * w);
      m1 = fmaxf(m1, (float)panel[r][c + 1] * w);
    }
    float* pmrow = pm + ((size_t)bh * 32 + qt) * SK + c;
    pmrow[0] = m0;
    pmrow[1] = m1;
  }
}

// ---- target_score: out[b][k] = sum_h max_qt pm[b*16+h][qt][k] ----
__global__ __launch_bounds__(256) void tscore_kernel(const float* __restrict__ pm,
                                                     float* __restrict__ out) {
  int bb = blockIdx.x;  // 64 = 4 b x 16 k-chunks
  int b = bb >> 4, kq = bb & 15;
  int t = threadIdx.x;
  int kl = t & 63, hg = t >> 6;  // 4 h-groups x 64 k
  int k = kq * 64 + kl;
  float s = 0.f;
#pragma unroll
  for (int hh = hg * 4; hh < hg * 4 + 4; ++hh) {
    const float* p = pm + ((size_t)(b * H_ + hh) * 32) * SK + k;
    float mx = 0.f;
#pragma unroll
    for (int qt = 0; qt < 32; ++qt) mx = fmaxf(mx, p[(size_t)qt * SK]);
    s += mx;
  }
  __shared__ float red[4][64];
  red[hg][kl] = s;
  __syncthreads();
  if (t < 64)
    out[(size_t)B_ * SQ * E_ + b * SK + kq * 64 + t] =
        red[0][t] + red[1][t] + red[2][t] + red[3][t];
}

extern "C" void kernel_launch(void* const* d_in, const int* in_sizes, int n_in,
                              void* d_out, int out_size, void* d_ws, size_t ws_size,
                              hipStream_t stream) {
  const float* dp_emb = (const float*)d_in[0];
  const float* dp_mask = (const float*)d_in[1];
  const float* K = (const float*)d_in[2];
  const float* V = (const float*)d_in[3];
  const float* M = (const float*)d_in[4];
  const float* Wq = (const float*)d_in[5];
  const float* bq = (const float*)d_in[6];
  float* out = (float*)d_out;

  char* ws = (char*)d_ws;
  half_t* q_h = (half_t*)(ws);                    // 8 MB  [BH,Sq,64]
  half_t* k_hn = (half_t*)(ws + (8ull << 20));    // 8 MB  [BH,Sk,64] (negated)
  half_t* vt_h = (half_t*)(ws + (16ull << 20));   // 8 MB  [BH,64,Sk]
  half_t* emb_h = (half_t*)(ws + (24ull << 20));  // 8 MB  [B*Sq,E]
  half_t* wq_h = (half_t*)(ws + (32ull << 20));   // 2 MB  [E,E]
  float* pm = (float*)(ws + (34ull << 20));       // 8 MB  [BH,32,Sk] colmax partials

  prep_kernel<<<QW_BLOCKS + B_ * H_ * 16, 256, 0, stream>>>(dp_emb, Wq, K, V, emb_h, wq_h,
                                                            k_hn, vt_h);
  proj_kernel<<<1024, 256, 0, stream>>>(emb_h, wq_h, bq, q_h);
  attn_kernel<<<B_ * H_ * (SQ / 32), 512, 0, stream>>>(q_h, k_hn, vt_h, M, dp_mask, out, pm);
  tscore_kernel<<<64, 256, 0, stream>>>(pm, out);
}